// Round 7
// baseline (189.392 us; speedup 1.0000x reference)
//
#include <hip/hip_runtime.h>

#define T_STEPS 20
#define BATCH   65536
#define HIDN    64
#define GATES   256
#define HSTR    72       // hl row stride (bf16 elems)

typedef __bf16 bf16x8 __attribute__((ext_vector_type(8)));
typedef float  f32x4  __attribute__((ext_vector_type(4)));
typedef float  f32x2  __attribute__((ext_vector_type(2)));

#if __has_builtin(__builtin_amdgcn_exp2f)
#define EXP2F(x) __builtin_amdgcn_exp2f(x)
#else
#define EXP2F(x) exp2f(x)
#endif
#if __has_builtin(__builtin_amdgcn_rcpf)
#define RCPF(x) __builtin_amdgcn_rcpf(x)
#else
#define RCPF(x) (1.0f / (x))
#endif

__device__ __forceinline__ float sigmoid_f(float x) {
    return RCPF(1.0f + EXP2F(x * -1.4426950408889634f));
}
__device__ __forceinline__ float tanh_f(float x) {
    return 1.0f - 2.0f * RCPF(1.0f + EXP2F(x * 2.8853900817779268f));
}

// WG = 4 waves, 32 batch rows as TWO independent 16-row m-blocks per wave.
// Wave jtw owns hidden quarter [16*jtw,16*jtw+16): computes gate tiles
// {jtw,4+jtw,8+jtw,12+jtw} for both m-blocks, sharing the 8 register-resident
// W_hh B-fragments. Two m-blocks = 2x per-wave ILP against the same per-step
// dependency chain (ds_read -> MFMA -> trans chain -> ds_write -> barrier),
// and half the barriers per row vs the 16-row version.
// VGPR budget ~120 (acc 32 + cst 8 + xc 16 + bfr 32 + w/bc 12 + addr/temps).
// __launch_bounds__(256,4): R5 proved min-waves=8 forces a 32-VGPR clamp
// and catastrophic spill; 4 leaves the allocator room, runtime occupancy
// comes from the grid (2048 WGs).
__global__ __launch_bounds__(256, 4)
void Encoder_6949257085628_kernel(const float* __restrict__ obs,
                                  const float* __restrict__ W_emb,
                                  const float* __restrict__ b_emb,
                                  const float* __restrict__ W_ih,
                                  const float* __restrict__ W_hh,
                                  const float* __restrict__ b_ih,
                                  const float* __restrict__ b_hh,
                                  float* __restrict__ out) {
    __shared__ float wcbc[GATES * 3];                    // 3 KB
    __shared__ __align__(16) __bf16 hlb[2][32 * HSTR];   // 2 x 4.5 KB, dbuf

    const int tid  = threadIdx.x;
    const int jtw  = tid >> 6;       // wave index = hidden-quarter
    const int lane = tid & 63;
    const int q    = lane >> 4;      // 0..3
    const int c16  = lane & 15;

    // ---- fold embedding into gate map: Wc (256x2), bc (256) ----
    {
        int g = tid;  // exactly 256 threads
        float a0 = 0.f, a1 = 0.f, ab = 0.f;
        for (int e = 0; e < 64; ++e) {
            float wie = W_ih[g * 64 + e];
            a0 = fmaf(wie, W_emb[e * 2 + 0], a0);
            a1 = fmaf(wie, W_emb[e * 2 + 1], a1);
            ab = fmaf(wie, b_emb[e], ab);
        }
        wcbc[g * 3 + 0] = a0;
        wcbc[g * 3 + 1] = a1;
        wcbc[g * 3 + 2] = ab + b_ih[g] + b_hh[g];
    }

    // ---- load this wave's 8 W_hh B-fragments into registers ----
    // B[k][n] = W_hh[n][k]; frag (tile,ks): lane holds n = tile*16+c16,
    // k = ks*32 + q*8 + j  (8 consecutive fp32 of one W_hh row).
    bf16x8 bfr[4][2];
    #pragma unroll
    for (int f = 0; f < 4; ++f) {
        const int rowW = (f * 4 + jtw) * 16 + c16;   // gate column
        #pragma unroll
        for (int ks = 0; ks < 2; ++ks) {
            const float* p = W_hh + rowW * 64 + ks * 32 + q * 8;
            f32x4 lo = *(const f32x4*)p;
            f32x4 hi = *(const f32x4*)(p + 4);
            bf16x8 b;
            b[0] = (__bf16)lo[0]; b[1] = (__bf16)lo[1];
            b[2] = (__bf16)lo[2]; b[3] = (__bf16)lo[3];
            b[4] = (__bf16)hi[0]; b[5] = (__bf16)hi[1];
            b[6] = (__bf16)hi[2]; b[7] = (__bf16)hi[3];
            bfr[f][ks] = b;
        }
    }
    __syncthreads();   // wcbc staged

    // per-lane x->gate constants for this wave's 4 gate columns
    float w0v[4], w1v[4], bcv[4];
    #pragma unroll
    for (int f = 0; f < 4; ++f) {
        int col = (f * 4 + jtw) * 16 + c16;
        w0v[f] = wcbc[col * 3 + 0];
        w1v[f] = wcbc[col * 3 + 1];
        bcv[f] = wcbc[col * 3 + 2];
    }

    const int rbw  = blockIdx.x * 32;           // this WG's 32 batch rows
    const int hOff = jtw * 16 + c16;            // this lane's hidden index

    float cst[2][4];
    #pragma unroll
    for (int m = 0; m < 2; ++m)
        #pragma unroll
        for (int r = 0; r < 4; ++r) cst[m][r] = 0.f;

    // x for t=0
    f32x2 xc[2][4];
    #pragma unroll
    for (int m = 0; m < 2; ++m)
        #pragma unroll
        for (int r = 0; r < 4; ++r)
            xc[m][r] = *(const f32x2*)&obs[(size_t)(rbw + m * 16 + q * 4 + r) * 2];

    #pragma unroll 1
    for (int t = 0; t < T_STEPS; ++t) {
        // gate init: x-contribution + bias (fp32); consumes xc
        f32x4 acc[2][4];
        #pragma unroll
        for (int m = 0; m < 2; ++m)
            #pragma unroll
            for (int f = 0; f < 4; ++f)
                #pragma unroll
                for (int r = 0; r < 4; ++r)
                    acc[m][f][r] = fmaf(xc[m][r][1], w1v[f],
                                   fmaf(xc[m][r][0], w0v[f], bcv[f]));

        // prefetch next step's x into xc (already consumed above)
        {
            int tn = (t + 1 < T_STEPS) ? t + 1 : t;
            const float* ob = obs + (size_t)tn * (BATCH * 2);
            #pragma unroll
            for (int m = 0; m < 2; ++m)
                #pragma unroll
                for (int r = 0; r < 4; ++r)
                    xc[m][r] = *(const f32x2*)&ob[(size_t)(rbw + m * 16 + q * 4 + r) * 2];
        }

        // recurrent GEMM for both m-blocks (h==0 at t=0)
        if (t > 0) {
            const __bf16* hp = hlb[(t & 1) ^ 1];
            bf16x8 a0[2], a1[2];
            #pragma unroll
            for (int m = 0; m < 2; ++m) {
                a0[m] = *(const bf16x8*)&hp[(m * 16 + c16) * HSTR + q * 8];
                a1[m] = *(const bf16x8*)&hp[(m * 16 + c16) * HSTR + 32 + q * 8];
            }
            #pragma unroll
            for (int f = 0; f < 4; ++f) {
                acc[0][f] = __builtin_amdgcn_mfma_f32_16x16x32_bf16(a0[0], bfr[f][0], acc[0][f], 0, 0, 0);
                acc[1][f] = __builtin_amdgcn_mfma_f32_16x16x32_bf16(a0[1], bfr[f][0], acc[1][f], 0, 0, 0);
                acc[0][f] = __builtin_amdgcn_mfma_f32_16x16x32_bf16(a1[0], bfr[f][1], acc[0][f], 0, 0, 0);
                acc[1][f] = __builtin_amdgcn_mfma_f32_16x16x32_bf16(a1[1], bfr[f][1], acc[1][f], 0, 0, 0);
            }
        }

        // activations + state update; rows m*16+q*4+r, hidden hOff
        __bf16* hw = hlb[t & 1];
        #pragma unroll
        for (int m = 0; m < 2; ++m) {
            #pragma unroll
            for (int r = 0; r < 4; ++r) {
                float ig = sigmoid_f(acc[m][0][r]);
                float fg = sigmoid_f(acc[m][1][r]);
                float gg = tanh_f(acc[m][2][r]);
                float og = sigmoid_f(acc[m][3][r]);
                float cc = fmaf(fg, cst[m][r], ig * gg);
                cst[m][r] = cc;
                float h = og * tanh_f(cc);
                if (t < T_STEPS - 1) {
                    hw[(m * 16 + q * 4 + r) * HSTR + hOff] = (__bf16)h;
                } else {
                    out[(size_t)(rbw + m * 16 + q * 4 + r) * HIDN + hOff] = h;
                }
            }
        }

        __syncthreads();  // h quarters exchanged across the 4 waves
    }
}

extern "C" void kernel_launch(void* const* d_in, const int* in_sizes, int n_in,
                              void* d_out, int out_size, void* d_ws, size_t ws_size,
                              hipStream_t stream) {
    const float* obs   = (const float*)d_in[0];
    const float* W_emb = (const float*)d_in[1];
    const float* b_emb = (const float*)d_in[2];
    const float* W_ih  = (const float*)d_in[3];
    const float* W_hh  = (const float*)d_in[4];
    const float* b_ih  = (const float*)d_in[5];
    const float* b_hh  = (const float*)d_in[6];
    float* out = (float*)d_out;

    dim3 grid(BATCH / 32);   // 2048 WGs x 32 rows
    dim3 block(256);
    Encoder_6949257085628_kernel<<<grid, block, 0, stream>>>(
        obs, W_emb, b_emb, W_ih, W_hh, b_ih, b_hh, out);
}

// Round 8
// 116.887 us; speedup vs baseline: 1.6203x; 1.6203x over previous
//
#include <hip/hip_runtime.h>

#define T_STEPS 20
#define BATCH   65536
#define HIDN    64
#define GATES   256
#define CHUNKS  2        // 16-row chunks per WG -> 2048 WGs = 8/CU
#define HSTR    72       // hl row stride (bf16 elems); 144B = 9*16B, keeps b128 aligned

typedef __bf16 bf16x8 __attribute__((ext_vector_type(8)));
typedef float  f32x4  __attribute__((ext_vector_type(4)));
typedef float  f32x2  __attribute__((ext_vector_type(2)));
typedef unsigned int uint32;

#define L2E 1.4426950408889634f

#if __has_builtin(__builtin_amdgcn_exp2f)
#define EXP2F(x) __builtin_amdgcn_exp2f(x)
#else
#define EXP2F(x) exp2f(x)
#endif
#if __has_builtin(__builtin_amdgcn_rcpf)
#define RCPF(x) __builtin_amdgcn_rcpf(x)
#else
#define RCPF(x) (1.0f / (x))
#endif

__device__ __forceinline__ uint32 pack2bf16(float a, float b) {
    unsigned short ua = __builtin_bit_cast(unsigned short, (__bf16)a);
    unsigned short ub = __builtin_bit_cast(unsigned short, (__bf16)b);
    return (uint32)ua | ((uint32)ub << 16);
}

// R6 skeleton (best: 136us): WG = 4 waves = 16 rows/chunk, wave jtw owns
// hidden quarter; 8 W_hh B-frags register-resident; h through dbuf LDS,
// one barrier/step; 2048 WGs = 8 WGs/CU.
// New this round (issue-work cuts):
//  * x-contribution via a 3rd MFMA slice: A=[x0,x1,0..], B=[w0,w1,0..],
//    C-in = bias broadcast  -> kills the 32-fma x-init per step.
//  * log2(e) folded into staged weights: rows i,f,o scaled by -L2E, row g by
//    +2*L2E -> exp2 consumes MFMA output directly (kills 16 muls/step).
//  * A-frag ds_read hoisted to just after the barrier (software pipeline);
//    t=0 / t=19 peeled so the 18-iter inner loop is branch-free.
// VGPR budget ~114 (bfr 32 + bxf 16 + bcc 16 + a0c/a1c 8 + acc 16 + misc).
// launch_bounds(256,4): R5/R7 showed forcing higher occupancy clamps VGPRs
// and spills (FETCH/WRITE balloon is the tripwire).
__global__ __launch_bounds__(256, 4)
void Encoder_6949257085628_kernel(const float* __restrict__ obs,
                                  const float* __restrict__ W_emb,
                                  const float* __restrict__ b_emb,
                                  const float* __restrict__ W_ih,
                                  const float* __restrict__ W_hh,
                                  const float* __restrict__ b_ih,
                                  const float* __restrict__ b_hh,
                                  float* __restrict__ out) {
    __shared__ float wcbc[GATES * 3];                    // 3 KB (scaled Wc,bc)
    __shared__ __align__(16) __bf16 hlb[2][16 * HSTR];   // 2 x 2.25 KB, dbuf

    const int tid  = threadIdx.x;
    const int jtw  = tid >> 6;       // wave index = hidden-quarter = gate class per f
    const int lane = tid & 63;
    const int q    = lane >> 4;      // 0..3
    const int c16  = lane & 15;

    // ---- fold embedding into gate map with log2e scaling ----
    // gate class of g: 0=i,1=f,2=g,3=o ; scale: i,f,o -> -L2E ; g -> +2*L2E
    {
        int g = tid;  // exactly 256 threads
        float sf = ((g >> 6) == 2) ? (2.0f * L2E) : (-L2E);
        float a0 = 0.f, a1 = 0.f, ab = 0.f;
        for (int e = 0; e < 64; ++e) {
            float wie = W_ih[g * 64 + e];
            a0 = fmaf(wie, W_emb[e * 2 + 0], a0);
            a1 = fmaf(wie, W_emb[e * 2 + 1], a1);
            ab = fmaf(wie, b_emb[e], ab);
        }
        wcbc[g * 3 + 0] = a0 * sf;
        wcbc[g * 3 + 1] = a1 * sf;
        wcbc[g * 3 + 2] = (ab + b_ih[g] + b_hh[g]) * sf;
    }

    // ---- this wave's 8 W_hh B-fragments, scaled, in registers ----
    // col = f*64 + jtw*16 + c16 -> gate class = f, so scale is per-f.
    bf16x8 bfr[4][2];
    #pragma unroll
    for (int f = 0; f < 4; ++f) {
        const float sf = (f == 2) ? (2.0f * L2E) : (-L2E);
        const int rowW = f * 64 + jtw * 16 + c16;
        #pragma unroll
        for (int ks = 0; ks < 2; ++ks) {
            const float* p = W_hh + rowW * 64 + ks * 32 + q * 8;
            f32x4 lo = *(const f32x4*)p;
            f32x4 hi = *(const f32x4*)(p + 4);
            bf16x8 b;
            b[0] = (__bf16)(lo[0] * sf); b[1] = (__bf16)(lo[1] * sf);
            b[2] = (__bf16)(lo[2] * sf); b[3] = (__bf16)(lo[3] * sf);
            b[4] = (__bf16)(hi[0] * sf); b[5] = (__bf16)(hi[1] * sf);
            b[6] = (__bf16)(hi[2] * sf); b[7] = (__bf16)(hi[3] * sf);
            bfr[f][ks] = b;
        }
    }
    __syncthreads();   // wcbc staged

    // ---- x->gate MFMA operands: B=[w0,w1,0..] (q==0 lanes), C-in = bc ----
    bf16x8 bxf[4];
    f32x4  bcc[4];
    #pragma unroll
    for (int f = 0; f < 4; ++f) {
        int col = f * 64 + jtw * 16 + c16;
        uint32 pk = pack2bf16(wcbc[col * 3 + 0], wcbc[col * 3 + 1]);
        uint32 e0 = (q == 0) ? pk : 0u;
        uint32 z[4] = {e0, 0u, 0u, 0u};
        bxf[f] = __builtin_bit_cast(bf16x8, z);
        float bcs = wcbc[col * 3 + 2];
        bcc[f] = f32x4{bcs, bcs, bcs, bcs};
    }

    const int wgBase = blockIdx.x * (16 * CHUNKS);
    const int hOff   = jtw * 16 + c16;          // this lane's hidden index

    #pragma unroll 1
    for (int c = 0; c < CHUNKS; ++c) {
        const int rbw = wgBase + c * 16;
        __syncthreads();   // protects hlb reuse across chunks

        float cst[4];
        #pragma unroll
        for (int r = 0; r < 4; ++r) cst[r] = 0.f;

        // every lane tracks x of row c16 (only q==0 lanes feed the MFMA)
        f32x2 xc = *(const f32x2*)&obs[(size_t)(rbw + c16) * 2];
        bf16x8 a0c, a1c;   // h A-frags, read right after each barrier

        // activation + store, shared by all steps
        auto act_store = [&](f32x4 (&acc)[4], __bf16* hw, bool last) {
            #pragma unroll
            for (int r = 0; r < 4; ++r) {
                float ig = RCPF(1.0f + EXP2F(acc[0][r]));
                float fg = RCPF(1.0f + EXP2F(acc[1][r]));
                float gg = fmaf(-2.0f, RCPF(1.0f + EXP2F(acc[2][r])), 1.0f);
                float og = RCPF(1.0f + EXP2F(acc[3][r]));
                float cc = fmaf(fg, cst[r], ig * gg);
                cst[r] = cc;
                float th = fmaf(-2.0f, RCPF(1.0f + EXP2F(cc * (2.0f * L2E))), 1.0f);
                float h  = og * th;
                if (!last) {
                    hw[(q * 4 + r) * HSTR + hOff] = (__bf16)h;
                } else {
                    out[(size_t)(rbw + q * 4 + r) * HIDN + hOff] = h;
                }
            }
        };
        auto build_ax = [&](f32x2 xv) -> bf16x8 {
            uint32 pk = pack2bf16(xv[0], xv[1]);
            uint32 e0 = (q == 0) ? pk : 0u;
            uint32 z[4] = {e0, 0u, 0u, 0u};
            return __builtin_bit_cast(bf16x8, z);
        };

        // ---- t = 0 (no h): gates = x-MFMA + bias ----
        {
            bf16x8 ax = build_ax(xc);
            f32x4 acc[4];
            #pragma unroll
            for (int f = 0; f < 4; ++f)
                acc[f] = __builtin_amdgcn_mfma_f32_16x16x32_bf16(ax, bxf[f], bcc[f], 0, 0, 0);
            xc = *(const f32x2*)&obs[(size_t)(BATCH * 2) + (size_t)(rbw + c16) * 2];
            act_store(acc, hlb[0], false);
            __syncthreads();
            a0c = *(const bf16x8*)&hlb[0][c16 * HSTR + q * 8];
            a1c = *(const bf16x8*)&hlb[0][c16 * HSTR + 32 + q * 8];
        }

        // ---- t = 1..18, branch-free ----
        #pragma unroll 1
        for (int t = 1; t < T_STEPS - 1; ++t) {
            bf16x8 ax = build_ax(xc);
            f32x4 acc[4];
            #pragma unroll
            for (int f = 0; f < 4; ++f) {
                acc[f] = __builtin_amdgcn_mfma_f32_16x16x32_bf16(ax,  bxf[f],    bcc[f], 0, 0, 0);
                acc[f] = __builtin_amdgcn_mfma_f32_16x16x32_bf16(a0c, bfr[f][0], acc[f], 0, 0, 0);
                acc[f] = __builtin_amdgcn_mfma_f32_16x16x32_bf16(a1c, bfr[f][1], acc[f], 0, 0, 0);
            }
            xc = *(const f32x2*)&obs[(size_t)(t + 1) * (BATCH * 2) + (size_t)(rbw + c16) * 2];
            act_store(acc, hlb[t & 1], false);
            __syncthreads();
            a0c = *(const bf16x8*)&hlb[t & 1][c16 * HSTR + q * 8];
            a1c = *(const bf16x8*)&hlb[t & 1][c16 * HSTR + 32 + q * 8];
        }

        // ---- t = 19: write fp32 output ----
        {
            bf16x8 ax = build_ax(xc);
            f32x4 acc[4];
            #pragma unroll
            for (int f = 0; f < 4; ++f) {
                acc[f] = __builtin_amdgcn_mfma_f32_16x16x32_bf16(ax,  bxf[f],    bcc[f], 0, 0, 0);
                acc[f] = __builtin_amdgcn_mfma_f32_16x16x32_bf16(a0c, bfr[f][0], acc[f], 0, 0, 0);
                acc[f] = __builtin_amdgcn_mfma_f32_16x16x32_bf16(a1c, bfr[f][1], acc[f], 0, 0, 0);
            }
            act_store(acc, nullptr, true);
        }
    }
}

extern "C" void kernel_launch(void* const* d_in, const int* in_sizes, int n_in,
                              void* d_out, int out_size, void* d_ws, size_t ws_size,
                              hipStream_t stream) {
    const float* obs   = (const float*)d_in[0];
    const float* W_emb = (const float*)d_in[1];
    const float* b_emb = (const float*)d_in[2];
    const float* W_ih  = (const float*)d_in[3];
    const float* W_hh  = (const float*)d_in[4];
    const float* b_ih  = (const float*)d_in[5];
    const float* b_hh  = (const float*)d_in[6];
    float* out = (float*)d_out;

    dim3 grid(BATCH / (16 * CHUNKS));  // 2048 WGs = 8 per CU
    dim3 block(256);
    Encoder_6949257085628_kernel<<<grid, block, 0, stream>>>(
        obs, W_emb, b_emb, W_ih, W_hh, b_ih, b_hh, out);
}

// Round 9
// 112.543 us; speedup vs baseline: 1.6828x; 1.0386x over previous
//
#include <hip/hip_runtime.h>

#define T_STEPS 20
#define BATCH   65536
#define HIDN    64
#define GATES   256
#define CHUNKS  2        // two 32-row chunks per WG -> 1024 WGs = 4/CU resident
#define HSTR    72       // hl row stride (bf16); 144B keeps b128 alignment, breaks pow2

typedef __bf16 bf16x8 __attribute__((ext_vector_type(8)));
typedef float  f32x4  __attribute__((ext_vector_type(4)));
typedef float  f32x2  __attribute__((ext_vector_type(2)));
typedef unsigned int uint32;
typedef uint32 uint32x4 __attribute__((ext_vector_type(4)));

#define L2E 1.4426950408889634f

#if __has_builtin(__builtin_amdgcn_exp2f)
#define EXP2F(x) __builtin_amdgcn_exp2f(x)
#else
#define EXP2F(x) exp2f(x)
#endif
#if __has_builtin(__builtin_amdgcn_rcpf)
#define RCPF(x) __builtin_amdgcn_rcpf(x)
#else
#define RCPF(x) (1.0f / (x))
#endif

__device__ __forceinline__ uint32 pack2bf16(float a, float b) {
    unsigned short ua = __builtin_bit_cast(unsigned short, (__bf16)a);
    unsigned short ub = __builtin_bit_cast(unsigned short, (__bf16)b);
    return (uint32)ua | ((uint32)ub << 16);
}

// R8 skeleton + 2 independent 16-row m-blocks per wave (WG = 32 rows):
//  - wave jtw owns hidden quarter; 8 scaled W_hh B-frags register-resident.
//  - x-contribution AND bias via one MFMA per (m,f): A=[x0,x1,1,1,0..],
//    B=[w0,w1,bc_hi,bc_lo,0..] (bc split bf16 hi/lo, err ~1e-5), C-in = 0.
//  - log2e folded into all staged weights (i,f,o: -L2E ; g: +2*L2E).
//  - 8 independent activation chains + 2 MFMA chains per wave per step;
//    barriers per row halved vs R8.
// Register diet keeps peak ~120: no bcc (bias in B-frag), bxf as 2 packed
// dwords/f, ax word1 is a 1-reg lane constant, A-frags read just-in-time.
// amdgpu_waves_per_eu(4,4): pin min AND max to 4 waves/EU so the allocator
// gets the full 128-VGPR budget and cannot repeat R7's clamp-to-64 + spill.
__global__ __launch_bounds__(256)
__attribute__((amdgpu_waves_per_eu(4, 4)))
void Encoder_6949257085628_kernel(const float* __restrict__ obs,
                                  const float* __restrict__ W_emb,
                                  const float* __restrict__ b_emb,
                                  const float* __restrict__ W_ih,
                                  const float* __restrict__ W_hh,
                                  const float* __restrict__ b_ih,
                                  const float* __restrict__ b_hh,
                                  float* __restrict__ out) {
    __shared__ float wcbc[GATES * 3];                    // 3 KB (scaled Wc,bc)
    __shared__ __align__(16) __bf16 hlb[2][32 * HSTR];   // 2 x 4.5 KB, dbuf

    const int tid  = threadIdx.x;
    const int jtw  = tid >> 6;       // wave index = hidden-quarter
    const int lane = tid & 63;
    const int q    = lane >> 4;      // 0..3 (K-group)
    const int c16  = lane & 15;
    const bool qz  = (q == 0);

    // ---- fold embedding into gate map with log2e scaling ----
    {
        int g = tid;  // exactly 256 threads
        float sf = ((g >> 6) == 2) ? (2.0f * L2E) : (-L2E);
        float a0 = 0.f, a1 = 0.f, ab = 0.f;
        for (int e = 0; e < 64; ++e) {
            float wie = W_ih[g * 64 + e];
            a0 = fmaf(wie, W_emb[e * 2 + 0], a0);
            a1 = fmaf(wie, W_emb[e * 2 + 1], a1);
            ab = fmaf(wie, b_emb[e], ab);
        }
        wcbc[g * 3 + 0] = a0 * sf;
        wcbc[g * 3 + 1] = a1 * sf;
        wcbc[g * 3 + 2] = (ab + b_ih[g] + b_hh[g]) * sf;
    }

    // ---- this wave's 8 W_hh B-fragments, scaled, in registers ----
    bf16x8 bfr[4][2];
    #pragma unroll
    for (int f = 0; f < 4; ++f) {
        const float sf = (f == 2) ? (2.0f * L2E) : (-L2E);
        const int rowW = f * 64 + jtw * 16 + c16;
        #pragma unroll
        for (int ks = 0; ks < 2; ++ks) {
            const float* p = W_hh + rowW * 64 + ks * 32 + q * 8;
            f32x4 lo = *(const f32x4*)p;
            f32x4 hi = *(const f32x4*)(p + 4);
            bf16x8 b;
            b[0] = (__bf16)(lo[0] * sf); b[1] = (__bf16)(lo[1] * sf);
            b[2] = (__bf16)(lo[2] * sf); b[3] = (__bf16)(lo[3] * sf);
            b[4] = (__bf16)(hi[0] * sf); b[5] = (__bf16)(hi[1] * sf);
            b[6] = (__bf16)(hi[2] * sf); b[7] = (__bf16)(hi[3] * sf);
            bfr[f][ks] = b;
        }
    }
    __syncthreads();   // wcbc staged

    // ---- x/bias B-frag words (per f): [w0,w1 | bc_hi,bc_lo | 0..], q==0 ----
    uint32 bxw0[4], bxw1[4];
    #pragma unroll
    for (int f = 0; f < 4; ++f) {
        int col = f * 64 + jtw * 16 + c16;
        float w0s = wcbc[col * 3 + 0];
        float w1s = wcbc[col * 3 + 1];
        float bcs = wcbc[col * 3 + 2];
        float blo = bcs - (float)((__bf16)bcs);
        bxw0[f] = qz ? pack2bf16(w0s, w1s) : 0u;
        bxw1[f] = qz ? pack2bf16(bcs, blo) : 0u;
    }
    const uint32 axw1 = qz ? 0x3F803F80u : 0u;   // [1.0,1.0] bf16, K-slots 2,3

    const int wgBase = blockIdx.x * (32 * CHUNKS);
    const int hOff   = jtw * 16 + c16;           // this lane's hidden index

    #pragma unroll 1
    for (int c = 0; c < CHUNKS; ++c) {
        const int rbw = wgBase + c * 32;
        __syncthreads();   // protects hlb reuse across chunks

        float cst[2][4];
        #pragma unroll
        for (int m = 0; m < 2; ++m)
            #pragma unroll
            for (int r = 0; r < 4; ++r) cst[m][r] = 0.f;

        // lane tracks x of row (m*16 + c16); only q==0 lanes feed the MFMA
        f32x2 xc[2];
        #pragma unroll
        for (int m = 0; m < 2; ++m)
            xc[m] = *(const f32x2*)&obs[(size_t)(rbw + m * 16 + c16) * 2];

        auto ax_of = [&](f32x2 xv) -> bf16x8 {
            uint32 w0 = qz ? pack2bf16(xv[0], xv[1]) : 0u;
            return __builtin_bit_cast(bf16x8, uint32x4{w0, axw1, 0u, 0u});
        };
        auto bx_of = [&](int f) -> bf16x8 {
            return __builtin_bit_cast(bf16x8, uint32x4{bxw0[f], bxw1[f], 0u, 0u});
        };
        auto act_store = [&](f32x4 (&acc)[4], int m, __bf16* hw, bool last) {
            #pragma unroll
            for (int r = 0; r < 4; ++r) {
                float ig = RCPF(1.0f + EXP2F(acc[0][r]));
                float fg = RCPF(1.0f + EXP2F(acc[1][r]));
                float gg = fmaf(-2.0f, RCPF(1.0f + EXP2F(acc[2][r])), 1.0f);
                float og = RCPF(1.0f + EXP2F(acc[3][r]));
                float cc = fmaf(fg, cst[m][r], ig * gg);
                cst[m][r] = cc;
                float th = fmaf(-2.0f, RCPF(1.0f + EXP2F(cc * (2.0f * L2E))), 1.0f);
                float h  = og * th;
                if (!last) {
                    hw[(m * 16 + q * 4 + r) * HSTR + hOff] = (__bf16)h;
                } else {
                    out[(size_t)(rbw + m * 16 + q * 4 + r) * HIDN + hOff] = h;
                }
            }
        };

        bf16x8 a0c[2], a1c[2];   // h A-frags, read right after each barrier

        // ---- t = 0 (no h): gates = x/bias MFMA only ----
        {
            f32x4 acc[2][4];
            #pragma unroll
            for (int m = 0; m < 2; ++m) {
                bf16x8 ax = ax_of(xc[m]);
                #pragma unroll
                for (int f = 0; f < 4; ++f)
                    acc[m][f] = __builtin_amdgcn_mfma_f32_16x16x32_bf16(
                        ax, bx_of(f), f32x4{0.f, 0.f, 0.f, 0.f}, 0, 0, 0);
            }
            #pragma unroll
            for (int m = 0; m < 2; ++m)
                xc[m] = *(const f32x2*)&obs[(size_t)(BATCH * 2) + (size_t)(rbw + m * 16 + c16) * 2];
            act_store(acc[0], 0, hlb[0], false);
            act_store(acc[1], 1, hlb[0], false);
            __syncthreads();
            #pragma unroll
            for (int m = 0; m < 2; ++m) {
                a0c[m] = *(const bf16x8*)&hlb[0][(m * 16 + c16) * HSTR + q * 8];
                a1c[m] = *(const bf16x8*)&hlb[0][(m * 16 + c16) * HSTR + 32 + q * 8];
            }
        }

        // ---- t = 1..18, branch-free ----
        #pragma unroll 1
        for (int t = 1; t < T_STEPS - 1; ++t) {
            f32x4 acc[2][4];
            #pragma unroll
            for (int m = 0; m < 2; ++m) {
                bf16x8 ax = ax_of(xc[m]);
                #pragma unroll
                for (int f = 0; f < 4; ++f) {
                    acc[m][f] = __builtin_amdgcn_mfma_f32_16x16x32_bf16(
                        ax, bx_of(f), f32x4{0.f, 0.f, 0.f, 0.f}, 0, 0, 0);
                    acc[m][f] = __builtin_amdgcn_mfma_f32_16x16x32_bf16(
                        a0c[m], bfr[f][0], acc[m][f], 0, 0, 0);
                    acc[m][f] = __builtin_amdgcn_mfma_f32_16x16x32_bf16(
                        a1c[m], bfr[f][1], acc[m][f], 0, 0, 0);
                }
            }
            #pragma unroll
            for (int m = 0; m < 2; ++m)
                xc[m] = *(const f32x2*)&obs[(size_t)(t + 1) * (BATCH * 2) + (size_t)(rbw + m * 16 + c16) * 2];
            act_store(acc[0], 0, hlb[t & 1], false);
            act_store(acc[1], 1, hlb[t & 1], false);
            __syncthreads();
            #pragma unroll
            for (int m = 0; m < 2; ++m) {
                a0c[m] = *(const bf16x8*)&hlb[t & 1][(m * 16 + c16) * HSTR + q * 8];
                a1c[m] = *(const bf16x8*)&hlb[t & 1][(m * 16 + c16) * HSTR + 32 + q * 8];
            }
        }

        // ---- t = 19: write fp32 output ----
        {
            f32x4 acc[2][4];
            #pragma unroll
            for (int m = 0; m < 2; ++m) {
                bf16x8 ax = ax_of(xc[m]);
                #pragma unroll
                for (int f = 0; f < 4; ++f) {
                    acc[m][f] = __builtin_amdgcn_mfma_f32_16x16x32_bf16(
                        ax, bx_of(f), f32x4{0.f, 0.f, 0.f, 0.f}, 0, 0, 0);
                    acc[m][f] = __builtin_amdgcn_mfma_f32_16x16x32_bf16(
                        a0c[m], bfr[f][0], acc[m][f], 0, 0, 0);
                    acc[m][f] = __builtin_amdgcn_mfma_f32_16x16x32_bf16(
                        a1c[m], bfr[f][1], acc[m][f], 0, 0, 0);
                }
            }
            act_store(acc[0], 0, nullptr, true);
            act_store(acc[1], 1, nullptr, true);
        }
    }
}

extern "C" void kernel_launch(void* const* d_in, const int* in_sizes, int n_in,
                              void* d_out, int out_size, void* d_ws, size_t ws_size,
                              hipStream_t stream) {
    const float* obs   = (const float*)d_in[0];
    const float* W_emb = (const float*)d_in[1];
    const float* b_emb = (const float*)d_in[2];
    const float* W_ih  = (const float*)d_in[3];
    const float* W_hh  = (const float*)d_in[4];
    const float* b_ih  = (const float*)d_in[5];
    const float* b_hh  = (const float*)d_in[6];
    float* out = (float*)d_out;

    dim3 grid(BATCH / (32 * CHUNKS));  // 1024 WGs = 4 per CU, all resident
    dim3 block(256);
    Encoder_6949257085628_kernel<<<grid, block, 0, stream>>>(
        obs, W_emb, b_emb, W_ih, W_hh, b_ih, b_hh, out);
}